// Round 1
// baseline (95.545 us; speedup 1.0000x reference)
//
#include <hip/hip_runtime.h>
#include <math.h>

#define WSZ 11
#define PADH 5
#define TILE 64
#define RPT 16          // rows per thread
#define SPAN 74         // TILE + 2*PADH
#define STRIDE 76       // padded LDS row stride (floats)

struct GaussW { float g[WSZ]; };

__device__ __forceinline__ void hrow(const float* __restrict__ pa,
                                     const float* __restrict__ pb,
                                     const GaussW& W,
                                     float& o0, float& o1, float& o2,
                                     float& o3, float& o4) {
    float s0 = 0.f, s1 = 0.f, s2 = 0.f, s3 = 0.f, s4 = 0.f;
#pragma unroll
    for (int j = 0; j < WSZ; ++j) {
        float a = pa[j], b = pb[j];
        float w = W.g[j];
        float wa = w * a, wb = w * b;
        s0 += wa;
        s1 += wb;
        s2 = fmaf(wa, a, s2);
        s3 = fmaf(wb, b, s3);
        s4 = fmaf(wa, b, s4);
    }
    o0 = s0; o1 = s1; o2 = s2; o3 = s3; o4 = s4;
}

__global__ __launch_bounds__(256, 3) void ssim_main(
    const float* __restrict__ img1, const float* __restrict__ img2,
    float* __restrict__ partials, GaussW W)
{
    __shared__ float sA[SPAN * STRIDE];
    __shared__ float sB[SPAN * STRIDE];
    __shared__ float red[4];

    const int bx = blockIdx.x;        // 0..63: tile within plane
    const int plane = blockIdx.y;     // 0..47: n*c plane
    const int tileX = bx & 7, tileY = bx >> 3;
    const int c0 = tileX * TILE, r0 = tileY * TILE;
    const int tid = threadIdx.x;

    const float* baseA = img1 + (size_t)plane * 262144;
    const float* baseB = img2 + (size_t)plane * 262144;

    // ---- stage 74x74 halo tiles (zero padding outside the plane) ----
    for (int idx = tid; idx < SPAN * SPAN; idx += 256) {
        int rr = idx / SPAN;
        int cc = idx - rr * SPAN;
        int gr = r0 - PADH + rr;
        int gc = c0 - PADH + cc;
        bool ok = (gr >= 0) && (gr < 512) && (gc >= 0) && (gc < 512);
        int gi = gr * 512 + gc;
        float a = ok ? baseA[gi] : 0.f;
        float b = ok ? baseB[gi] : 0.f;
        sA[rr * STRIDE + cc] = a;
        sB[rr * STRIDE + cc] = b;
    }
    __syncthreads();

    // ---- per-thread: one column, RPT rows, vertical ring in registers ----
    const int col = tid & 63;
    const int strip = tid >> 6;         // 0..3
    const int lr0 = strip * RPT;        // first window row (tile coords)

    float h0[WSZ], h1[WSZ], h2[WSZ], h3[WSZ], h4[WSZ];

#pragma unroll
    for (int p = 0; p < 10; ++p) {
        const float* pa = sA + (lr0 + p) * STRIDE + col;
        const float* pb = sB + (lr0 + p) * STRIDE + col;
        hrow(pa, pb, W, h0[p], h1[p], h2[p], h3[p], h4[p]);
    }

    float local = 0.f;
#pragma unroll
    for (int i = 0; i < RPT; ++i) {
        const int ns = (10 + i) % WSZ;  // constant after unroll
        const float* pa = sA + (lr0 + 10 + i) * STRIDE + col;
        const float* pb = sB + (lr0 + 10 + i) * STRIDE + col;
        hrow(pa, pb, W, h0[ns], h1[ns], h2[ns], h3[ns], h4[ns]);

        float mu1 = 0.f, mu2 = 0.f, e11 = 0.f, e22 = 0.f, e12 = 0.f;
#pragma unroll
        for (int k = 0; k < WSZ; ++k) {
            const int s = (i + k) % WSZ; // constant after unroll
            float w = W.g[k];
            mu1 = fmaf(w, h0[s], mu1);
            mu2 = fmaf(w, h1[s], mu2);
            e11 = fmaf(w, h2[s], e11);
            e22 = fmaf(w, h3[s], e22);
            e12 = fmaf(w, h4[s], e12);
        }
        float mu1sq = mu1 * mu1;
        float mu2sq = mu2 * mu2;
        float mu12  = mu1 * mu2;
        float s11 = e11 - mu1sq;
        float s22 = e22 - mu2sq;
        float s12 = e12 - mu12;
        float num = (2.f * mu12 + 1e-4f) * (2.f * s12 + 9e-4f);
        float den = (mu1sq + mu2sq + 1e-4f) * (s11 + s22 + 9e-4f);
        float r = __builtin_amdgcn_rcpf(den);
        r = r * (2.f - den * r);        // one NR step
        local = fmaf(num, r, local);
    }

    // ---- block reduction: wave shfl + 4 partials ----
#pragma unroll
    for (int off = 32; off; off >>= 1)
        local += __shfl_down(local, off, 64);
    if ((tid & 63) == 0) red[strip] = local;
    __syncthreads();
    if (tid == 0)
        partials[plane * 64 + bx] = red[0] + red[1] + red[2] + red[3];
}

__global__ __launch_bounds__(256) void ssim_final(
    const float* __restrict__ partials, float* __restrict__ out)
{
    __shared__ double red[4];
    const int tid = threadIdx.x;
    double s = 0.0;
    for (int i = tid; i < 3072; i += 256) s += (double)partials[i];
#pragma unroll
    for (int off = 32; off; off >>= 1)
        s += __shfl_down(s, off, 64);
    if ((tid & 63) == 0) red[tid >> 6] = s;
    __syncthreads();
    if (tid == 0)
        out[0] = (float)((red[0] + red[1] + red[2] + red[3]) / 12582912.0);
}

extern "C" void kernel_launch(void* const* d_in, const int* in_sizes, int n_in,
                              void* d_out, int out_size, void* d_ws, size_t ws_size,
                              hipStream_t stream) {
    const float* img1 = (const float*)d_in[0];
    const float* img2 = (const float*)d_in[1];
    float* out = (float*)d_out;
    float* partials = (float*)d_ws;   // 3072 floats

    GaussW W;
    double g[WSZ], sum = 0.0;
    for (int i = 0; i < WSZ; ++i) {
        double d = (double)(i - PADH);
        g[i] = exp(-(d * d) / 4.5);
        sum += g[i];
    }
    for (int i = 0; i < WSZ; ++i) W.g[i] = (float)(g[i] / sum);

    ssim_main<<<dim3(64, 48), 256, 0, stream>>>(img1, img2, partials, W);
    ssim_final<<<1, 256, 0, stream>>>(partials, out);
}

// Round 2
// 91.146 us; speedup vs baseline: 1.0483x; 1.0483x over previous
//
#include <hip/hip_runtime.h>
#include <math.h>

#define WSZ 11
#define PAD 5
#define TW 64            // tile width (outputs)
#define TH 48            // tile height (outputs)
#define HROWS 58         // TH + 2*PAD
#define PSTR 65          // LDS plane row stride (floats)
#define PSZ (HROWS * PSTR)   // 3770 floats per plane
#define RSTRIP 12        // output rows per V-thread
#define NPLANE 262144    // 512*512
#define SCALE 1073741824.0   // 2^30
#define NPIX 12582912.0      // 16*3*512*512

struct GaussW { float g[WSZ]; };

// guarded aligned float4 row load with zero padding outside [0,512)
__device__ __forceinline__ float4 g4(const float* __restrict__ row, int s, bool rv) {
    float4 r;
    if (!rv) { r.x = r.y = r.z = r.w = 0.f; return r; }
    if (s >= 0 && s <= 508) {
        return *(const float4*)(row + s);
    }
    r.x = (s + 0 >= 0 && s + 0 < 512) ? row[s + 0] : 0.f;
    r.y = (s + 1 >= 0 && s + 1 < 512) ? row[s + 1] : 0.f;
    r.z = (s + 2 >= 0 && s + 2 < 512) ? row[s + 2] : 0.f;
    r.w = (s + 3 >= 0 && s + 3 < 512) ? row[s + 3] : 0.f;
    return r;
}

__global__ __launch_bounds__(256, 2) void ssim_main(
    const float* __restrict__ img1, const float* __restrict__ img2,
    unsigned long long* __restrict__ acc, GaussW W)
{
    __shared__ float sP[5 * PSZ];
    __shared__ float red[4];

    const int tid = threadIdx.x;
    const int bx = blockIdx.x;        // 0..87 : 8 x-tiles * 11 y-tiles
    const int plane = blockIdx.y;     // 0..47
    const int tx = bx & 7, ty = bx >> 3;
    const int c0 = tx * TW;
    const int r0 = ty * TH;

    const float* baseA = img1 + (size_t)plane * NPLANE;
    const float* baseB = img2 + (size_t)plane * NPLANE;

    // ---------------- Phase H: horizontal blur, global -> LDS planes --------
    if (tid < HROWS * 4) {
        const int pr  = tid >> 2;     // 0..57 plane row
        const int seg = tid & 3;      // 16-col segment
        const int gr  = r0 - PAD + pr;
        const bool rv = (gr >= 0) && (gr < 512);
        const float* rowA = baseA + gr * 512;
        const float* rowB = baseB + gr * 512;
        const int sbase = c0 + seg * 16 - 8;   // 4-aligned

        float a[32], b[32];
#pragma unroll
        for (int k = 0; k < 8; ++k) {
            float4 va = g4(rowA, sbase + 4 * k, rv);
            float4 vb = g4(rowB, sbase + 4 * k, rv);
            a[4 * k + 0] = va.x; a[4 * k + 1] = va.y;
            a[4 * k + 2] = va.z; a[4 * k + 3] = va.w;
            b[4 * k + 0] = vb.x; b[4 * k + 1] = vb.y;
            b[4 * k + 2] = vb.z; b[4 * k + 3] = vb.w;
        }

#pragma unroll
        for (int i = 0; i < 16; ++i) {
            float s0 = 0.f, s1 = 0.f, s2 = 0.f, s3 = 0.f, s4 = 0.f;
#pragma unroll
            for (int j = 0; j < WSZ; ++j) {
                float aa = a[i + 3 + j];
                float bb = b[i + 3 + j];
                float w  = W.g[j];
                float wa = w * aa, wb = w * bb;
                s0 += wa;
                s1 += wb;
                s2 = fmaf(wa, aa, s2);
                s3 = fmaf(wb, bb, s3);
                s4 = fmaf(wa, bb, s4);
            }
            const int idx = pr * PSTR + seg * 16 + i;
            sP[idx]           = s0;
            sP[PSZ     + idx] = s1;
            sP[2 * PSZ + idx] = s2;
            sP[3 * PSZ + idx] = s3;
            sP[4 * PSZ + idx] = s4;
        }
    }
    __syncthreads();

    // ---------------- Phase V: vertical blur via register ring --------------
    const int col = tid & 63;
    const int strip = tid >> 6;          // 0..3
    const int lr0 = strip * RSTRIP;      // first output row (tile coords)

    float h0[WSZ], h1[WSZ], h2[WSZ], h3[WSZ], h4[WSZ];

#pragma unroll
    for (int p = 0; p < 10; ++p) {
        const int off = (lr0 + p) * PSTR + col;
        h0[p] = sP[off];
        h1[p] = sP[PSZ     + off];
        h2[p] = sP[2 * PSZ + off];
        h3[p] = sP[3 * PSZ + off];
        h4[p] = sP[4 * PSZ + off];
    }

    float local = 0.f;
#pragma unroll
    for (int i = 0; i < RSTRIP; ++i) {
        const int ns = (10 + i) % WSZ;   // constant after unroll
        const int off = (lr0 + 10 + i) * PSTR + col;
        h0[ns] = sP[off];
        h1[ns] = sP[PSZ     + off];
        h2[ns] = sP[2 * PSZ + off];
        h3[ns] = sP[3 * PSZ + off];
        h4[ns] = sP[4 * PSZ + off];

        float mu1 = 0.f, mu2 = 0.f, e11 = 0.f, e22 = 0.f, e12 = 0.f;
#pragma unroll
        for (int k = 0; k < WSZ; ++k) {
            const int s = (i + k) % WSZ; // constant after unroll
            float w = W.g[k];
            mu1 = fmaf(w, h0[s], mu1);
            mu2 = fmaf(w, h1[s], mu2);
            e11 = fmaf(w, h2[s], e11);
            e22 = fmaf(w, h3[s], e22);
            e12 = fmaf(w, h4[s], e12);
        }
        float mu1sq = mu1 * mu1;
        float mu2sq = mu2 * mu2;
        float mu12  = mu1 * mu2;
        float s11 = e11 - mu1sq;
        float s22 = e22 - mu2sq;
        float s12 = e12 - mu12;
        float num = (2.f * mu12 + 1e-4f) * (2.f * s12 + 9e-4f);
        float den = (mu1sq + mu2sq + 1e-4f) * (s11 + s22 + 9e-4f);
        float rr = __builtin_amdgcn_rcpf(den);
        rr = rr * (2.f - den * rr);      // one NR step
        const int gr = r0 + lr0 + i;
        float v = num * rr;
        local += (gr < 512) ? v : 0.f;   // ragged last y-tile
    }

    // ---------------- block reduction -> fixed-point global atomic ----------
#pragma unroll
    for (int off = 32; off; off >>= 1)
        local += __shfl_down(local, off, 64);
    if ((tid & 63) == 0) red[tid >> 6] = local;
    __syncthreads();
    if (tid == 0) {
        float bs = red[0] + red[1] + red[2] + red[3];
        unsigned long long q = (unsigned long long)__double2ll_rn((double)bs * SCALE);
        atomicAdd(acc, q);
    }
}

__global__ void ssim_final(const unsigned long long* __restrict__ acc,
                           float* __restrict__ out)
{
    if (threadIdx.x == 0)
        out[0] = (float)((double)(*acc) * (1.0 / SCALE) / NPIX);
}

extern "C" void kernel_launch(void* const* d_in, const int* in_sizes, int n_in,
                              void* d_out, int out_size, void* d_ws, size_t ws_size,
                              hipStream_t stream) {
    const float* img1 = (const float*)d_in[0];
    const float* img2 = (const float*)d_in[1];
    float* out = (float*)d_out;
    unsigned long long* acc = (unsigned long long*)d_ws;

    GaussW W;
    double g[WSZ], sum = 0.0;
    for (int i = 0; i < WSZ; ++i) {
        double d = (double)(i - PAD);
        g[i] = exp(-(d * d) / 4.5);
        sum += g[i];
    }
    for (int i = 0; i < WSZ; ++i) W.g[i] = (float)(g[i] / sum);

    hipMemsetAsync(d_ws, 0, sizeof(unsigned long long), stream);
    ssim_main<<<dim3(88, 48), 256, 0, stream>>>(img1, img2, acc, W);
    ssim_final<<<1, 64, 0, stream>>>(acc, out);
}